// Round 4
// baseline (149.444 us; speedup 1.0000x reference)
//
#include <hip/hip_runtime.h>
#include <float.h>
#include <math.h>
#include <stdint.h>

// VQ-VAE VectorQuantizer — round 4: 16-wave blocks (1 block/CU, 50% occupancy
// target), 64KB chunks shared by all 16 waves, loss computed from MFMA scores
// (no z re-read in phase 2).
//
// z_e: (32, 256, 32, 32) fp32, weight: (1024, 256) fp32
// out: quantized_st (8388608 f32) + loss (1) + perplexity (1)
//
// vq_main4: grid 256 x 1024thr. Block = 128 z. Wave (zq, cq): 32 z (2 B-sets)
//   x 256 codes (16 tiles). Chunk = 8 tiles (2 per cq) = 64 KB, double-buffered
//   via global_load_lds. score[k][n] = wsq[k] - 2 w_k.z_n in MFMA accumulator.
//   loss_n = min_score_n + ||z_n||^2 (fp32, from phase A).
//
// ws: [0,4096) wsq f32 | [4096,8192) counts u32 | [8192,8200) loss_sum f32, done u32
//     [16384, +524288) cbfrag bf16

#define NB   32
#define NC   256
#define NHW  1024
#define NK   1024
#define NELEM (NB*NC*NHW)
#define GRID_MAIN 256

typedef __attribute__((ext_vector_type(8))) short bf16x8;
typedef __attribute__((ext_vector_type(4))) float f32x4;

__device__ __forceinline__ unsigned short f2bf(float f) {   // RTN fp32->bf16
    unsigned u = __float_as_uint(f);
    u += 0x7FFFu + ((u >> 16) & 1u);
    return (unsigned short)(u >> 16);
}

// ---------------- K1: prep = wsq + pack + zero ----------------
__global__ __launch_bounds__(256) void vq_prep(const float* __restrict__ w,
                                               float* __restrict__ wsq,
                                               unsigned short* __restrict__ cb,
                                               unsigned int* __restrict__ counts,
                                               unsigned int* __restrict__ lossdone) {
    const int tid = threadIdx.x, b = blockIdx.x;
    const int lane = tid & 63, wv = tid >> 6;
    {   // wsq for code k = b*4 + wv
        const int k = b * 4 + wv;
        const float* row = w + k * NC;
        float s = 0.f;
#pragma unroll
        for (int p = 0; p < 4; ++p) { float v = row[lane + p * 64]; s = fmaf(v, v, s); }
#pragma unroll
        for (int off = 32; off; off >>= 1) s += __shfl_down(s, off, 64);
        if (lane == 0) wsq[k] = s;
    }
    // pack: one 16B A-frag piece per thread (blocks 0..127)
    const int gt = b * 256 + tid;
    if (gt < 32768) {
        const int t = gt >> 9, p = gt & 511;
        const int cc = p >> 6, l = p & 63;
        const int n = l & 15, quad = l >> 4;
        const float* src = w + (t * 16 + n) * NC + cc * 32 + quad * 8;
        const float4 f0 = *(const float4*)src;
        const float4 f1 = *(const float4*)(src + 4);
        union { unsigned short u[8]; uint4 v; } pk;
        pk.u[0] = f2bf(-2.f * f0.x); pk.u[1] = f2bf(-2.f * f0.y);
        pk.u[2] = f2bf(-2.f * f0.z); pk.u[3] = f2bf(-2.f * f0.w);
        pk.u[4] = f2bf(-2.f * f1.x); pk.u[5] = f2bf(-2.f * f1.y);
        pk.u[6] = f2bf(-2.f * f1.z); pk.u[7] = f2bf(-2.f * f1.w);
        *(uint4*)(cb + (size_t)t * 4096 + cc * 512 + (size_t)l * 8) = pk.v;
    }
    if (b == 128) {
#pragma unroll
        for (int i = 0; i < 4; ++i) counts[tid * 4 + i] = 0u;
        if (tid < 2) lossdone[tid] = 0u;
    }
}

// ---------------- K2: main ----------------
__global__ __launch_bounds__(1024, 4) void vq_main4(const float* __restrict__ z,
                                                    const float* __restrict__ w,
                                                    const float* __restrict__ wsq,
                                                    const unsigned short* __restrict__ cb,
                                                    unsigned int* __restrict__ counts,
                                                    unsigned int* __restrict__ lossdone,
                                                    float* __restrict__ out) {
    __shared__ __align__(16) char cbuf[2][65536];   // 128 KB double-buffered chunks
    // post-loop aliases in cbuf[0] (chunk 7 reads only cbuf[1]):
    int*   fidx  = (int*)(cbuf[0]);            // 128 ints
    float* pscr  = (float*)(cbuf[0] + 512);    // [4][128]
    int*   pidx  = (int*)(cbuf[0] + 2560);     // [4][128]
    float* zsqs  = (float*)(cbuf[0] + 4608);   // [128]
    float* lred  = (float*)(cbuf[0] + 5120);   // [2]
    int*   lflag = (int*)(cbuf[0] + 5184);
    float* red2  = (float*)(cbuf[0] + 5200);   // [4]

    const int tid  = threadIdx.x;
    const int wv   = tid >> 6, lane = tid & 63;
    const int n    = lane & 15, quad = lane >> 4;
    const int zq   = wv & 3;          // which 32 z of the block's 128
    const int cq   = wv >> 2;         // which 256 codes (tiles cq*16..+15)
    const int b    = blockIdx.x;
    const int img  = b >> 3;
    const int hw0  = (b & 7) << 7;    // 128 hw per block
    const float* zb = z + (size_t)img * (NC * NHW);
    const char* cbb = (const char*)cb;

    // chunk ch: slot s = i*2 + (tid>>9) holds tile (i*16 + ch*2 + (tid>>9));
    // 1024 threads x 4 x 16B = 64 KB.
#define STAGE(ch)                                                              \
    {                                                                          \
        _Pragma("unroll")                                                      \
        for (int i = 0; i < 4; ++i) {                                          \
            const int t = i * 16 + (ch) * 2 + (tid >> 9);                      \
            const char* gsrc = cbb + (size_t)t * 8192 + (tid & 511) * 16;      \
            char* ldst = cbuf[(ch) & 1] + i * 16384 + tid * 16;                \
            __builtin_amdgcn_global_load_lds(                                  \
                (const __attribute__((address_space(1))) unsigned int*)        \
                    (uintptr_t)gsrc,                                           \
                (__attribute__((address_space(3))) unsigned int*)              \
                    (uint32_t)(uintptr_t)ldst,                                 \
                16, 0, 0);                                                     \
        }                                                                      \
    }

    STAGE(0);   // DMA overlaps phase A

    // ---- Phase A: 2 B-sets (32 z) in registers + fp32 ||z||^2 partials ----
    bf16x8 bfr[2][8];
    float zsqp[2] = {0.f, 0.f};
#pragma unroll
    for (int s = 0; s < 2; ++s) {
#pragma unroll
        for (int cc = 0; cc < 8; ++cc) {
            const float* zp = zb + (size_t)(cc * 32 + quad * 8) * NHW
                              + hw0 + zq * 32 + s * 16 + n;
            union { unsigned short u[8]; bf16x8 v; } pk;
#pragma unroll
            for (int j = 0; j < 8; ++j) {
                const float f = zp[(size_t)j * NHW];
                zsqp[s] = fmaf(f, f, zsqp[s]);
                pk.u[j] = f2bf(f);
            }
            bfr[s][cc] = pk.v;
        }
    }

    float bestv[2] = {FLT_MAX, FLT_MAX};
    int   besti[2] = {0, 0};

    for (int ch = 0; ch < 8; ++ch) {
        __syncthreads();                    // drains STAGE(ch)
        if (ch + 1 < 8) STAGE(ch + 1);
        const char* bufc = cbuf[ch & 1];
        const int kt0 = (cq * 16 + ch * 2) * 16;
        const int kt1 = kt0 + 16;
        const int so0 = (cq * 2) * 8192, so1 = so0 + 8192;
        f32x4 acc00 = *(const f32x4*)(wsq + kt0 + quad * 4);
        f32x4 acc01 = acc00;
        f32x4 acc10 = *(const f32x4*)(wsq + kt1 + quad * 4);
        f32x4 acc11 = acc10;
#pragma unroll
        for (int cc = 0; cc < 8; ++cc) {    // 2 A-reads feed 4 MFMAs
            const bf16x8 a0 = *(const bf16x8*)(bufc + so0 + cc * 1024 + lane * 16);
            const bf16x8 a1 = *(const bf16x8*)(bufc + so1 + cc * 1024 + lane * 16);
            acc00 = __builtin_amdgcn_mfma_f32_16x16x32_bf16(a0, bfr[0][cc], acc00, 0, 0, 0);
            acc01 = __builtin_amdgcn_mfma_f32_16x16x32_bf16(a0, bfr[1][cc], acc01, 0, 0, 0);
            acc10 = __builtin_amdgcn_mfma_f32_16x16x32_bf16(a1, bfr[0][cc], acc10, 0, 0, 0);
            acc11 = __builtin_amdgcn_mfma_f32_16x16x32_bf16(a1, bfr[1][cc], acc11, 0, 0, 0);
        }
#pragma unroll
        for (int r = 0; r < 4; ++r) {
            const int k0 = kt0 + quad * 4 + r, k1 = kt1 + quad * 4 + r;
            if (acc00[r] < bestv[0]) { bestv[0] = acc00[r]; besti[0] = k0; }
            if (acc01[r] < bestv[1]) { bestv[1] = acc01[r]; besti[1] = k0; }
            if (acc10[r] < bestv[0]) { bestv[0] = acc10[r]; besti[0] = k1; }
            if (acc11[r] < bestv[1]) { bestv[1] = acc11[r]; besti[1] = k1; }
        }
    }

    // ---- cross-quad reduce: argmin per set, fp32 zsq sum ----
#pragma unroll
    for (int s = 0; s < 2; ++s) {
        float bv = bestv[s]; int bi = besti[s]; float zs = zsqp[s];
#pragma unroll
        for (int off = 16; off <= 32; off <<= 1) {
            const float ov = __shfl_xor(bv, off, 64);
            const int   ok = __shfl_xor(bi, off, 64);
            if (ov < bv || (ov == bv && ok < bi)) { bv = ov; bi = ok; }
            zs += __shfl_xor(zs, off, 64);
        }
        bestv[s] = bv; besti[s] = bi; zsqp[s] = zs;
    }
    __syncthreads();                  // last ds_reads (chunk7, cbuf[1]) may still run; aliases in cbuf[0] are safe
    if (lane < 16) {
#pragma unroll
        for (int s = 0; s < 2; ++s) {
            const int zloc = zq * 32 + s * 16 + lane;
            pscr[cq * 128 + zloc] = bestv[s];
            pidx[cq * 128 + zloc] = besti[s];
            if (cq == 0) zsqs[zloc] = zsqp[s];
        }
    }
    __syncthreads();
    if (tid < 128) {   // combine code-quarters; histogram; loss from scores
        float bv = pscr[tid]; int bi = pidx[tid];
#pragma unroll
        for (int q = 1; q < 4; ++q) {
            const float v = pscr[q * 128 + tid];
            if (v < bv) { bv = v; bi = pidx[q * 128 + tid]; }
        }
        fidx[tid] = bi;
        atomicAdd(&counts[bi], 1u);
        float ln = bv + zsqs[tid];    // sum_c (q-z)^2 for this vector
#pragma unroll
        for (int off = 32; off; off >>= 1) ln += __shfl_down(ln, off, 64);
        if ((tid & 63) == 0) lred[tid >> 6] = ln;
    }
    __syncthreads();
    if (tid == 0) {
        atomicAdd((float*)lossdone, lred[0] + lred[1]);
        const unsigned old = __hip_atomic_fetch_add(&lossdone[1], 1u,
                                 __ATOMIC_ACQ_REL, __HIP_MEMORY_SCOPE_AGENT);
        lflag[0] = (old == GRID_MAIN - 1) ? 1 : 0;
    }

    // ---- Phase 2: gather codebook rows, stream out (no z re-read) ----
    {
        const int hwl = tid & 127;
        const int cg  = tid >> 7;          // c range [cg*32, cg*32+32)
        const int myk = fidx[hwl];
        const float* wr = w + myk * NC + cg * 32;
        float* ob = out + (size_t)img * (NC * NHW) + (size_t)(cg * 32) * NHW + hw0 + hwl;
#pragma unroll
        for (int p = 0; p < 8; ++p) {
            const float4 q4 = *(const float4*)(wr + p * 4);
            ob[(size_t)(p * 4 + 0) * NHW] = q4.x;
            ob[(size_t)(p * 4 + 1) * NHW] = q4.y;
            ob[(size_t)(p * 4 + 2) * NHW] = q4.z;
            ob[(size_t)(p * 4 + 3) * NHW] = q4.w;
        }
    }
    __syncthreads();
    if (lflag[0]) {   // last block: loss + perplexity
        if (tid < 256) {
            float s = 0.f;
#pragma unroll
            for (int p = 0; p < 4; ++p) {
                const unsigned c = __hip_atomic_load(&counts[tid + p * 256],
                                       __ATOMIC_RELAXED, __HIP_MEMORY_SCOPE_AGENT);
                const float pr = (float)c * (1.f / 32768.f);
                s = fmaf(pr, logf(pr + 1e-10f), s);
            }
#pragma unroll
            for (int off = 32; off; off >>= 1) s += __shfl_down(s, off, 64);
            if (lane == 0) red2[tid >> 6] = s;
        }
        __syncthreads();
        if (tid == 0) {
            const float tot = red2[0] + red2[1] + red2[2] + red2[3];
            const float ls = __hip_atomic_load((float*)lossdone,
                                 __ATOMIC_RELAXED, __HIP_MEMORY_SCOPE_AGENT);
            out[NELEM]     = ls * (1.25f / (float)NELEM);
            out[NELEM + 1] = expf(-tot);
        }
    }
}

extern "C" void kernel_launch(void* const* d_in, const int* in_sizes, int n_in,
                              void* d_out, int out_size, void* d_ws, size_t ws_size,
                              hipStream_t stream) {
    const float* z = (const float*)d_in[0];
    const float* w = (const float*)d_in[1];
    float* out = (float*)d_out;

    float*          wsq      = (float*)d_ws;
    unsigned int*   counts   = (unsigned int*)((char*)d_ws + 4096);
    unsigned int*   lossdone = (unsigned int*)((char*)d_ws + 8192);
    unsigned short* cbfrag   = (unsigned short*)((char*)d_ws + 16384);  // 512 KB

    vq_prep <<<256,       256,  0, stream>>>(w, wsq, cbfrag, counts, lossdone);
    vq_main4<<<GRID_MAIN, 1024, 0, stream>>>(z, w, wsq, cbfrag, counts, lossdone, out);
}